// Round 9
// baseline (102.364 us; speedup 1.0000x reference)
//
#include <hip/hip_runtime.h>
#include <hip/hip_bf16.h>
#include <math.h>

// Problem constants
#define BATCH   2048
#define TWO_B   4096
#define DIM     1024
#define NBLK2   1024          // 32x32 grid of 128x128 tiles
// 1 / (0.07 * ln(2)) : exp(s/T) = exp2(s * INV_T_LOG2E)
#define INV_T_LOG2E 20.60991907f
#define INV_T       14.285714285714286f

// s_waitcnt simm16 (gfx9 encoding): vmcnt[3:0] | expcnt[6:4] | lgkmcnt[11:8] | vmcnt[5:4]<<14
// don't-care exp (7) and lgkm (0xF); wait until <= N vmem outstanding.
#define WAITCNT_VM4 0x0F74
#define WAITCNT_VM0 0x0F70

typedef float f32x4 __attribute__((ext_vector_type(4)));
typedef long  i64x2 __attribute__((ext_vector_type(2)));

__device__ __forceinline__ void load_lds16(const void* g, void* l) {
    __builtin_amdgcn_global_load_lds(
        (const __attribute__((address_space(1))) void*)g,
        (__attribute__((address_space(3))) void*)l,
        16, 0, 0);
}

// ---------------------------------------------------------------------------
// Kernel 1: L2-normalize 4096 rows -> fp8 e4m3 z[4096][1024] (4 MB).
// Wave-per-row; zero-inits rowsum + completion counter. No fences.
// ---------------------------------------------------------------------------
__global__ __launch_bounds__(256) void normalize_kernel(
        const float* __restrict__ feat, char* __restrict__ z,
        float* __restrict__ rowsum, unsigned int* __restrict__ counter) {
    const int lane = threadIdx.x & 63;
    const int row  = blockIdx.x * 4 + (threadIdx.x >> 6);
    if (lane == 0) rowsum[row] = 0.0f;
    if (blockIdx.x == 0 && threadIdx.x == 0) *counter = 0u;

    const float* src = feat + (row < BATCH ? (size_t)row * (2 * DIM)
                                           : (size_t)(row - BATCH) * (2 * DIM) + DIM);
    float4 v[4];
    float ss = 0.0f;
    #pragma unroll
    for (int t = 0; t < 4; ++t) {
        v[t] = ((const float4*)src)[t * 64 + lane];
        ss += v[t].x * v[t].x + v[t].y * v[t].y + v[t].z * v[t].z + v[t].w * v[t].w;
    }
    #pragma unroll
    for (int off = 32; off; off >>= 1) ss += __shfl_xor(ss, off, 64);
    const float scale = 1.0f / fmaxf(sqrtf(ss), 1e-12f);
    int4 o;
    int* op = (int*)&o;
    #pragma unroll
    for (int t = 0; t < 4; ++t) {
        int lo = __builtin_amdgcn_cvt_pk_fp8_f32(v[t].x * scale, v[t].y * scale, 0, false);
        op[t]  = __builtin_amdgcn_cvt_pk_fp8_f32(v[t].z * scale, v[t].w * scale, lo, true);
    }
    ((int4*)(z + (size_t)row * DIM))[lane] = o;   // 64 lanes x 16 B = one row
}

// ---------------------------------------------------------------------------
// Kernel 2: full sim = z z^T in fp8 e4m3, 128x128 tiles, BK=64, dbuf LDS.
// R9 change: AITER-style K-loop — raw s_barrier + fine s_waitcnt vmcnt(4)
// (NEVER vmcnt(0) mid-loop), so prefetch loads stay in flight across the
// compute phase instead of being drained by __syncthreads' vmcnt(0).
// Invariant: each wave has exactly 4 of its own staging loads outstanding at
// loop top; vmcnt(4) after issuing 4 more waits precisely for the current
// buffer's loads. Barrier then makes all waves' cur-chunks visible.
// Carried from R8: XCD-aware block swizzle (FETCH 16.5->10.4 MB), XOR LDS
// swizzle (0 conflicts), LDS-transpose epilogue + coalesced 64-lane
// atomicAdd, fence-free last-block finalize.
// ---------------------------------------------------------------------------
__global__ __launch_bounds__(256) void gemm_fused(
        const char* __restrict__ z,
        float* __restrict__ rowsum,
        float* __restrict__ positives,
        unsigned int* __restrict__ counter,
        float* __restrict__ out) {
    __shared__ char smem[32768];     // 2x8KB sA dbuf | 2x8KB sB dbuf

    // XCD-aware swizzle: id&7 = round-robin XCD; 8x16 block region per XCD
    const int bid = blockIdx.x;
    const int xcd = bid & 7;
    const int t8  = bid >> 3;                   // 0..127 within region
    const int by  = (xcd >> 1) * 8 + (t8 & 7);
    const int bx  = (xcd & 1) * 16 + (t8 >> 3);
    const int rb  = by * 128;
    const int cb  = bx * 128;

    const int tid  = threadIdx.x;
    const int lane = tid & 63;
    const int wv   = tid >> 6;       // wave 0..3
    const int wr   = wv >> 1;        // wave row (0..1) -> 64-row subtile
    const int wc   = wv & 1;         // wave col (0..1) -> 64-col subtile
    const int q    = lane >> 4;      // quad 0..3
    const int mn   = lane & 15;

    char* sA0 = smem;                // sA[buf] = smem + buf*8192
    char* sB0 = smem + 16384;        // sB[buf] = smem + 16384 + buf*8192

    f32x4 acc[4][4] = {};

    const int lrow  = lane >> 2;                       // row within 16-row chunk
    const int lsegb = ((lane & 3) ^ ((lane >> 3) & 3)) * 16;   // fetch-side XOR swizzle
    const int rslot = (q ^ ((mn >> 1) & 3)) * 16;      // byte offset in 64-B row

    // per-wave staging chunks: ci = 2*wv, 2*wv+1 (16 rows x 64 B = 1 KB each)
    const size_t aoff0 = (size_t)(rb + (wv * 2 + 0) * 16 + lrow) * DIM + lsegb;
    const size_t aoff1 = (size_t)(rb + (wv * 2 + 1) * 16 + lrow) * DIM + lsegb;
    const size_t boff0 = (size_t)(cb + (wv * 2 + 0) * 16 + lrow) * DIM + lsegb;
    const size_t boff1 = (size_t)(cb + (wv * 2 + 1) * 16 + lrow) * DIM + lsegb;

    // preload K-tile 0 into buffer 0 (4 loads in flight)
    load_lds16(z + aoff0, sA0 + (wv * 2 + 0) * 1024);
    load_lds16(z + aoff1, sA0 + (wv * 2 + 1) * 1024);
    load_lds16(z + boff0, sB0 + (wv * 2 + 0) * 1024);
    load_lds16(z + boff1, sB0 + (wv * 2 + 1) * 1024);

    int cur = 0;
    #pragma unroll 2
    for (int t = 0; t < 16; ++t) {
        const int nxt = cur ^ 1;
        if (t < 15) {
            // prefetch next K-tile (outstanding: 4 cur + 4 nxt = 8)
            const int k0 = (t + 1) * 64;
            load_lds16(z + aoff0 + k0, sA0 + nxt * 8192 + (wv * 2 + 0) * 1024);
            load_lds16(z + aoff1 + k0, sA0 + nxt * 8192 + (wv * 2 + 1) * 1024);
            load_lds16(z + boff0 + k0, sB0 + nxt * 8192 + (wv * 2 + 0) * 1024);
            load_lds16(z + boff1 + k0, sB0 + nxt * 8192 + (wv * 2 + 1) * 1024);
            __builtin_amdgcn_s_waitcnt(WAITCNT_VM4);   // cur done; nxt in flight
        } else {
            __builtin_amdgcn_s_waitcnt(WAITCNT_VM0);   // last tile: drain all
        }
        asm volatile("" ::: "memory");
        __builtin_amdgcn_s_barrier();    // raw: no compiler vmcnt(0) drain
        asm volatile("" ::: "memory");

        const char* cA = sA0 + cur * 8192;
        const char* cB = sB0 + cur * 8192;
        long a0[4], a1[4], b0[4], b1[4];
        #pragma unroll
        for (int i = 0; i < 4; ++i) {
            i64x2 va = *(const i64x2*)&cA[(wr * 64 + i * 16 + mn) * 64 + rslot];
            a0[i] = va.x; a1[i] = va.y;
            i64x2 vb = *(const i64x2*)&cB[(wc * 64 + i * 16 + mn) * 64 + rslot];
            b0[i] = vb.x; b1[i] = vb.y;
        }
        #pragma unroll
        for (int i = 0; i < 4; ++i)
            #pragma unroll
            for (int j = 0; j < 4; ++j) {
                acc[i][j] = __builtin_amdgcn_mfma_f32_16x16x32_fp8_fp8(
                                a0[i], b0[j], acc[i][j], 0, 0, 0);
                acc[i][j] = __builtin_amdgcn_mfma_f32_16x16x32_fp8_fp8(
                                a1[i], b1[j], acc[i][j], 0, 0, 0);
            }
        asm volatile("" ::: "memory");
        __builtin_amdgcn_s_barrier();    // cur reads done before re-staging
        asm volatile("" ::: "memory");
        cur = nxt;
    }
    __syncthreads();   // full drain before epilogue reuses smem

    // ---- Epilogue (C/D layout col = lane&15, row = (lane>>4)*4 + reg) ----
    float* ep = (float*)smem + wv * (64 * 20);
    #pragma unroll
    for (int i = 0; i < 4; ++i) {
        #pragma unroll
        for (int reg = 0; reg < 4; ++reg) {
            const int r  = rb + wr * 64 + i * 16 + q * 4 + reg;
            const int pc = (r + BATCH) & (TWO_B - 1);
            float local = 0.0f;
            #pragma unroll
            for (int j = 0; j < 4; ++j) {
                const int c = cb + wc * 64 + j * 16 + mn;
                const float s = acc[i][j][reg];
                if (c == pc)   // unique writer per r
                    __hip_atomic_store(&positives[r], s, __ATOMIC_RELAXED,
                                       __HIP_MEMORY_SCOPE_AGENT);
                local += (c == r) ? 0.0f : exp2f(s * INV_T_LOG2E);
            }
            ep[(i * 16 + q * 4 + reg) * 20 + mn] = local;
        }
    }
    // wave-private read-back; one coalesced 64-lane atomic per wave
    {
        const float4 p0 = *(const float4*)&ep[lane * 20 + 0];
        const float4 p1 = *(const float4*)&ep[lane * 20 + 4];
        const float4 p2 = *(const float4*)&ep[lane * 20 + 8];
        const float4 p3 = *(const float4*)&ep[lane * 20 + 12];
        const float tot = (p0.x + p0.y + p0.z + p0.w) + (p1.x + p1.y + p1.z + p1.w)
                        + (p2.x + p2.y + p2.z + p2.w) + (p3.x + p3.y + p3.z + p3.w);
        atomicAdd(&rowsum[rb + wr * 64 + lane], tot);
    }

    // ---- fence-free last-block finalize (R7/R8, proven) ----
    __shared__ int amLast;
    __syncthreads();
    if (tid == 0) {
        unsigned int old = __hip_atomic_fetch_add(counter, 1u, __ATOMIC_RELAXED,
                                                  __HIP_MEMORY_SCOPE_AGENT);
        amLast = (old == NBLK2 - 1);
    }
    __syncthreads();
    if (amLast) {
        float acc2 = 0.0f;
        for (int r = tid; r < TWO_B; r += 256) {
            float rs = __hip_atomic_load(&rowsum[r], __ATOMIC_RELAXED,
                                         __HIP_MEMORY_SCOPE_AGENT);
            float p  = __hip_atomic_load(&positives[r], __ATOMIC_RELAXED,
                                         __HIP_MEMORY_SCOPE_AGENT);
            acc2 += logf(rs) - p * INV_T;
        }
        #pragma unroll
        for (int off = 32; off; off >>= 1) acc2 += __shfl_down(acc2, off, 64);
        __shared__ float s_part[4];
        if ((tid & 63) == 0) s_part[tid >> 6] = acc2;
        __syncthreads();
        if (tid == 0)
            out[0] = (s_part[0] + s_part[1] + s_part[2] + s_part[3]) * (1.0f / TWO_B);
    }
}

extern "C" void kernel_launch(void* const* d_in, const int* in_sizes, int n_in,
                              void* d_out, int out_size, void* d_ws, size_t ws_size,
                              hipStream_t stream) {
    const float* feat = (const float*)d_in[0];
    char* ws = (char*)d_ws;

    // workspace: z fp8[4096][1024] (4 MB) | rowsum f32[4096] | positives f32[4096] | counter
    char* zq              = ws;
    float* rowsum         = (float*)(ws + (size_t)TWO_B * DIM);
    float* positives      = rowsum + TWO_B;
    unsigned int* counter = (unsigned int*)(positives + TWO_B);
    float* out            = (float*)d_out;

    normalize_kernel<<<TWO_B / 4, 256, 0, stream>>>(feat, zq, rowsum, counter);
    gemm_fused<<<NBLK2, 256, 0, stream>>>(zq, rowsum, positives, counter, out);
}